// Round 1
// baseline (126.600 us; speedup 1.0000x reference)
//
#include <hip/hip_runtime.h>

#define IMG_H 896
#define IMG_W 1344
#define NPIX (IMG_H * IMG_W)   // 1,204,224 = 4704 * 256 exactly

// Per-pixel fused 3-layer MLP: 6 -> 32 -> 32 -> 3, relu after each layer.
// One pixel per thread, fully unrolled. Weights are read at compile-time
// constant offsets from uniform kernel-arg pointers -> compiler emits
// s_load_dwordx16 scalar loads; every FMA is v_fmac_f32 with an SGPR
// weight operand (no per-FMA vector-memory traffic).
__global__ __launch_bounds__(256) void mlp_pixel_kernel(
    const float* __restrict__ x,
    const float* __restrict__ w1, const float* __restrict__ b1,
    const float* __restrict__ w2, const float* __restrict__ b2,
    const float* __restrict__ w3, const float* __restrict__ b3,
    float* __restrict__ out)
{
    int p = blockIdx.x * 256 + threadIdx.x;
    if (p >= NPIX) return;

    // 6 input channels, 24 B / pixel, 8-B aligned -> 3x float2
    const float2* xp = reinterpret_cast<const float2*>(x + (size_t)p * 6);
    float2 x01 = xp[0];
    float2 x23 = xp[1];
    float2 x45 = xp[2];
    float xi[6] = {x01.x, x01.y, x23.x, x23.y, x45.x, x45.y};

    // ---- layer 1: 6 -> 32 ----
    float h1[32];
#pragma unroll
    for (int d = 0; d < 32; ++d) h1[d] = b1[d];
#pragma unroll
    for (int c = 0; c < 6; ++c) {
#pragma unroll
        for (int d = 0; d < 32; ++d)
            h1[d] = fmaf(xi[c], w1[c * 32 + d], h1[d]);
    }
#pragma unroll
    for (int d = 0; d < 32; ++d) h1[d] = fmaxf(h1[d], 0.0f);

    // ---- layer 2: 32 -> 32 (the 2048-FLOP hot loop) ----
    float h2[32];
#pragma unroll
    for (int d = 0; d < 32; ++d) h2[d] = b2[d];
#pragma unroll
    for (int c = 0; c < 32; ++c) {
#pragma unroll
        for (int d = 0; d < 32; ++d)
            h2[d] = fmaf(h1[c], w2[c * 32 + d], h2[d]);
    }
#pragma unroll
    for (int d = 0; d < 32; ++d) h2[d] = fmaxf(h2[d], 0.0f);

    // ---- layer 3: 32 -> 3 ----
    float o[3] = {b3[0], b3[1], b3[2]};
#pragma unroll
    for (int c = 0; c < 32; ++c) {
#pragma unroll
        for (int d = 0; d < 3; ++d)
            o[d] = fmaf(h2[c], w3[c * 3 + d], o[d]);
    }
#pragma unroll
    for (int d = 0; d < 3; ++d) o[d] = fmaxf(o[d], 0.0f);

    float* op = out + (size_t)p * 3;
    op[0] = o[0];
    op[1] = o[1];
    op[2] = o[2];
}

extern "C" void kernel_launch(void* const* d_in, const int* in_sizes, int n_in,
                              void* d_out, int out_size, void* d_ws, size_t ws_size,
                              hipStream_t stream) {
    const float* x  = (const float*)d_in[0];
    const float* w1 = (const float*)d_in[1];
    const float* b1 = (const float*)d_in[2];
    const float* w2 = (const float*)d_in[3];
    const float* b2 = (const float*)d_in[4];
    const float* w3 = (const float*)d_in[5];
    const float* b3 = (const float*)d_in[6];
    float* out = (float*)d_out;

    int grid = (NPIX + 255) / 256;  // 4704
    mlp_pixel_kernel<<<grid, 256, 0, stream>>>(x, w1, b1, w2, b2, w3, b3, out);
}